// Round 6
// baseline (879.004 us; speedup 1.0000x reference)
//
#include <hip/hip_runtime.h>
#include <hip/hip_bf16.h>

// Problem constants
#define N_TOK   576
#define MPAD    640            // padded to 5*128
#define DIM     1024
#define VOCAB   262400
#define BM      128
#define BN      256
#define BK      64
#define NTILE   (DIM/BK)       // 16
#define RB      5              // MPAD/BM row blocks
#define VBLKS   (VOCAB/BN)     // 1025
#define NWG     (RB*VBLKS)     // 5125
#define IGNORE_INDEX (-100)

typedef float  f32x4  __attribute__((ext_vector_type(4)));
typedef short  bf16x8 __attribute__((ext_vector_type(8)));
typedef unsigned short u16x8 __attribute__((ext_vector_type(8)));

#define AS1 __attribute__((address_space(1)))
#define AS3 __attribute__((address_space(3)))

__device__ __forceinline__ unsigned cvt_pk_bf16(float a, float b) {
  union { __hip_bfloat162 h; unsigned u; } c;
  c.h = __float22bfloat162_rn(make_float2(a, b));   // -> v_cvt_pk_bf16_f32
  return c.u;
}

// ---------- kernel 1: x fp32 -> bf16, rows [576,640) zero-padded ----------
__global__ void k_cvt_x(const float* __restrict__ x, unsigned short* __restrict__ xb) {
  int idx = blockIdx.x * 256 + threadIdx.x;     // 81920 threads * 8 elems
  long e0 = (long)idx * 8;
  int row = (int)(e0 >> 10);
  union { u16x8 v; unsigned u[4]; } o;
  if (row < N_TOK) {
    const float4 f0 = *(const float4*)(x + e0);
    const float4 f1 = *(const float4*)(x + e0 + 4);
    o.u[0] = cvt_pk_bf16(f0.x, f0.y);
    o.u[1] = cvt_pk_bf16(f0.z, f0.w);
    o.u[2] = cvt_pk_bf16(f1.x, f1.y);
    o.u[3] = cvt_pk_bf16(f1.z, f1.w);
  } else {
    o.u[0] = o.u[1] = o.u[2] = o.u[3] = 0u;
  }
  *(u16x8*)(xb + e0) = o.v;
}

// ---------- kernel 2: 8-phase GEMM + softcap + exp + row-sum ----------
// m201-style schedule: per K64-tile, 4 phases = one acc quadrant each
// {8 ds_read frags; staging slice; s_barrier; lgkmcnt(0); setprio(1);
//  8 MFMA; setprio(0); s_barrier}. Staging: q0=A(t+1) gload_lds,
// q1=B(t+2) global->reg (full-tile latency cover), q2/q3=cvt+ds_write
// B(t+1). Boundary: lgkm(0)+vmcnt(8) counted (B(t+2) stays in flight).
// A/B double-buffered (all hazards buffer-separated; phase barriers are
// scheduling-only). LDS chunk swizzle (j ^ (r&7)) -> conflict-free.
__global__ __launch_bounds__(512, 2) void k_gemm(
    const float* __restrict__ W,            // [VOCAB][DIM] fp32
    const unsigned short* __restrict__ Xb,  // [MPAD][DIM] bf16
    float* __restrict__ S)                  // [MPAD] running sum of exp(z-30)
{
  __shared__ unsigned short As[2 * BM * BK];   // 32 KB, swizzled
  __shared__ unsigned short Bs[2 * BN * BK];   // 64 KB, swizzled

  // ---- bijective XCD swizzle (m204), rb-fastest logical order ----
  const int qx = NWG / 8, rm = NWG % 8;     // 640, 5
  const int orig = blockIdx.x;
  const int xcd  = orig & 7;
  const int part = orig >> 3;
  const int bid  = (xcd < rm ? xcd * (qx + 1) : rm * (qx + 1) + (xcd - rm) * qx) + part;

  const int rb  = bid % RB;
  const int vb  = bid / RB;
  const int m0  = rb * BM;
  const long n0 = (long)vb * BN;

  const int t   = threadIdx.x;
  const int l   = t & 63;
  const int w   = t >> 6;                   // 0..7
  const int wm  = w >> 2, wn = w & 3;       // 2x4 wave grid, 64x64 per wave
  const int l15 = l & 15, lh = l >> 4;
  const int e8  = l15 & 7;

  // staging geometry: A 2 chunks/thread, B 4 chunks/thread (16B chunks)
  int aR[2], aKB[2];
  #pragma unroll
  for (int i = 0; i < 2; ++i) {
    int lin = t + i * 512;                  // 0..1023
    aR[i]  = lin >> 3;
    aKB[i] = (lin & 7) ^ (aR[i] & 7);       // pre-swizzled source chunk
  }
  int bR[4], bJ[4], bC[4];
  #pragma unroll
  for (int i = 0; i < 4; ++i) {
    int lin = t + i * 512;                  // 0..2047
    bR[i] = lin >> 3;                       // row 0..255
    bJ[i] = lin & 7;                        // linear source chunk
    bC[i] = bJ[i] ^ (bR[i] & 7);            // swizzled LDS slot
  }
  const unsigned short* agb[2];
  #pragma unroll
  for (int i = 0; i < 2; ++i) agb[i] = Xb + (size_t)(m0 + aR[i]) * DIM + aKB[i] * 8;
  const float* wgb[4];
  #pragma unroll
  for (int i = 0; i < 4; ++i) wgb[i] = W + (n0 + bR[i]) * DIM + bJ[i] * 8;

  const int ck0 = (lh ^ e8) * 8;            // swizzled frag chunk, kk=0
  const int ck1 = ((4 + lh) ^ e8) * 8;      // kk=1

  f32x4 acc[4][4];
  const f32x4 zero4 = {0.0f, 0.0f, 0.0f, 0.0f};
  #pragma unroll
  for (int i = 0; i < 4; ++i)
    #pragma unroll
    for (int j = 0; j < 4; ++j) acc[i][j] = zero4;

  float4 fb[2][4][2];                       // B(tau) lives in fb[tau&1]

  // ---- prologue: FIFO order A(0)x2, B(0)x8, B(1)x8 ----
  #pragma unroll
  for (int i = 0; i < 2; ++i)
    __builtin_amdgcn_global_load_lds((const AS1 void*)(agb[i]),
        (AS3 void*)(As + (t + i * 512) * 8), 16, 0, 0);
  #pragma unroll
  for (int i = 0; i < 4; ++i) {
    fb[0][i][0] = *(const float4*)(wgb[i]);
    fb[0][i][1] = *(const float4*)(wgb[i] + 4);
  }
  #pragma unroll
  for (int i = 0; i < 4; ++i) {
    fb[1][i][0] = *(const float4*)(wgb[i] + BK);
    fb[1][i][1] = *(const float4*)(wgb[i] + BK + 4);
  }
  #pragma unroll
  for (int i = 0; i < 4; ++i) {             // cvt B(0) -> Bs buf0
    union { u16x8 v; unsigned u[4]; } o;
    o.u[0] = cvt_pk_bf16(fb[0][i][0].x, fb[0][i][0].y);
    o.u[1] = cvt_pk_bf16(fb[0][i][0].z, fb[0][i][0].w);
    o.u[2] = cvt_pk_bf16(fb[0][i][1].x, fb[0][i][1].y);
    o.u[3] = cvt_pk_bf16(fb[0][i][1].z, fb[0][i][1].w);
    *(u16x8*)(Bs + bR[i] * BK + bC[i] * 8) = o.v;
  }
  asm volatile("s_waitcnt lgkmcnt(0)" ::: "memory");
  asm volatile("s_waitcnt vmcnt(8)" ::: "memory");   // A(0) landed; B(1) in flight
  __builtin_amdgcn_s_barrier();

  // ---- main: 16 tiles x 4 phases, fully unrolled (all indices static) ----
  #pragma unroll
  for (int kt = 0; kt < NTILE; ++kt) {
    const int rbuf = kt & 1;
    const int wbuf = rbuf ^ 1;
    #pragma unroll
    for (int q = 0; q < 4; ++q) {
      const int mh = q >> 1, nh = q & 1;    // acc quadrant
      // -- frag ds_reads (swizzled, conflict-free) --
      bf16x8 af[2][2], bfr[2][2];
      #pragma unroll
      for (int i = 0; i < 2; ++i) {
        const unsigned short* base = As + rbuf * (BM * BK)
                                        + (wm * 64 + mh * 32 + i * 16 + l15) * BK;
        af[i][0] = *(const bf16x8*)(base + ck0);
        af[i][1] = *(const bf16x8*)(base + ck1);
      }
      #pragma unroll
      for (int j = 0; j < 2; ++j) {
        const unsigned short* base = Bs + rbuf * (BN * BK)
                                        + (wn * 64 + nh * 32 + j * 16 + l15) * BK;
        bfr[j][0] = *(const bf16x8*)(base + ck0);
        bfr[j][1] = *(const bf16x8*)(base + ck1);
      }
      // -- staging slice --
      if (q == 0 && kt < NTILE - 1) {       // A(t+1) -> other buf (FIFO first)
        #pragma unroll
        for (int i = 0; i < 2; ++i)
          __builtin_amdgcn_global_load_lds(
              (const AS1 void*)(agb[i] + (kt + 1) * BK),
              (AS3 void*)(As + wbuf * (BM * BK) + (t + i * 512) * 8), 16, 0, 0);
      }
      if (q == 1 && kt < NTILE - 2) {       // B(t+2) -> fb[kt&1], used next tile
        #pragma unroll
        for (int i = 0; i < 4; ++i) {
          fb[rbuf][i][0] = *(const float4*)(wgb[i] + (kt + 2) * BK);
          fb[rbuf][i][1] = *(const float4*)(wgb[i] + (kt + 2) * BK + 4);
        }
      }
      if (q >= 2 && kt < NTILE - 1) {       // cvt+write B(t+1), 2 chunks/phase
        const int i0 = (q - 2) * 2;
        #pragma unroll
        for (int i = i0; i < i0 + 2; ++i) {
          union { u16x8 v; unsigned u[4]; } o;
          o.u[0] = cvt_pk_bf16(fb[wbuf][i][0].x, fb[wbuf][i][0].y);
          o.u[1] = cvt_pk_bf16(fb[wbuf][i][0].z, fb[wbuf][i][0].w);
          o.u[2] = cvt_pk_bf16(fb[wbuf][i][1].x, fb[wbuf][i][1].y);
          o.u[3] = cvt_pk_bf16(fb[wbuf][i][1].z, fb[wbuf][i][1].w);
          *(u16x8*)(Bs + wbuf * (BN * BK) + bR[i] * BK + bC[i] * 8) = o.v;
        }
      }
      // -- phase barrier + MFMA cluster --
      __builtin_amdgcn_s_barrier();
      asm volatile("s_waitcnt lgkmcnt(0)" ::: "memory");
      __builtin_amdgcn_sched_barrier(0);
      __builtin_amdgcn_s_setprio(1);
      #pragma unroll
      for (int kk = 0; kk < 2; ++kk)
        #pragma unroll
        for (int i = 0; i < 2; ++i)
          #pragma unroll
          for (int j = 0; j < 2; ++j)
            acc[mh*2 + i][nh*2 + j] = __builtin_amdgcn_mfma_f32_16x16x32_bf16(
                af[i][kk], bfr[j][kk], acc[mh*2 + i][nh*2 + j], 0, 0, 0);
      __builtin_amdgcn_s_setprio(0);
      if (q < 3) {
        __builtin_amdgcn_s_barrier();
      } else if (kt < NTILE - 1) {          // tile boundary: counted vmcnt
        asm volatile("s_waitcnt lgkmcnt(0)" ::: "memory");
        if (kt < NTILE - 2) asm volatile("s_waitcnt vmcnt(8)" ::: "memory");
        else                asm volatile("s_waitcnt vmcnt(0)" ::: "memory");
        __builtin_amdgcn_s_barrier();
      }
    }
  }

  // ---- epilogue: p = exp(z-30) = exp(-60/(exp(g/15)+1)), row sums, atomics
  // C frag layout: col = l&15 (vocab), row = (l>>4)*4 + jj (token)
  #pragma unroll
  for (int mi = 0; mi < 4; ++mi) {
    #pragma unroll
    for (int jj = 0; jj < 4; ++jj) {
      float s = 0.0f;
      #pragma unroll
      for (int ni = 0; ni < 4; ++ni) {
        float g   = acc[mi][ni][jj];
        float tp1 = __expf(g * (1.0f / 15.0f)) + 1.0f;
        s += __expf(-60.0f * __builtin_amdgcn_rcpf(tp1));
      }
      s += __shfl_xor(s, 1);
      s += __shfl_xor(s, 2);
      s += __shfl_xor(s, 4);
      s += __shfl_xor(s, 8);
      if (l15 == 0) {
        int row = m0 + wm * 64 + mi * 16 + lh * 4 + jj;
        atomicAdd(&S[row], s);              // padded rows land in S[576..640)
      }
    }
  }
}

// ---------- kernel 3: exact fp32 target logits ----------
__global__ void k_tgt(const float* __restrict__ x, const float* __restrict__ W,
                      const int* __restrict__ labels, float* __restrict__ tgt) {
  int n = blockIdx.x;
  int lab = labels[n];
  int t = threadIdx.x;                       // 256 threads * 4 floats = 1024
  float s = 0.0f;
  if (lab >= 0) {
    const float4 a = ((const float4*)(x + (size_t)n * DIM))[t];
    const float4 b = ((const float4*)(W + (size_t)lab * DIM))[t];
    s = a.x*b.x + a.y*b.y + a.z*b.z + a.w*b.w;
  }
  #pragma unroll
  for (int off = 32; off >= 1; off >>= 1) s += __shfl_xor(s, off);
  __shared__ float wsum[4];
  if ((t & 63) == 0) wsum[t >> 6] = s;
  __syncthreads();
  if (t == 0) {
    float d = wsum[0] + wsum[1] + wsum[2] + wsum[3];
    tgt[n] = (lab >= 0) ? 30.0f * tanhf(d * (1.0f / 30.0f)) : 0.0f;
  }
}

// ---------- kernel 4: final reduce -> loss ----------
__global__ void k_final(const float* __restrict__ S, const float* __restrict__ tgt,
                        const int* __restrict__ labels, float* __restrict__ out) {
  int t = threadIdx.x;
  float sum = 0.0f, cnt = 0.0f;
  for (int n = t; n < N_TOK; n += 256) {
    if (labels[n] != IGNORE_INDEX) {
      sum += 30.0f + __logf(S[n]) - tgt[n];  // lse = 30 + log(sum exp(z-30))
      cnt += 1.0f;
    }
  }
  #pragma unroll
  for (int off = 32; off >= 1; off >>= 1) {
    sum += __shfl_xor(sum, off);
    cnt += __shfl_xor(cnt, off);
  }
  __shared__ float as_[4], ac_[4];
  if ((t & 63) == 0) { as_[t >> 6] = sum; ac_[t >> 6] = cnt; }
  __syncthreads();
  if (t == 0) {
    float ts = as_[0] + as_[1] + as_[2] + as_[3];
    float tc = ac_[0] + ac_[1] + ac_[2] + ac_[3];
    out[0] = ts / tc;
  }
}

extern "C" void kernel_launch(void* const* d_in, const int* in_sizes, int n_in,
                              void* d_out, int out_size, void* d_ws, size_t ws_size,
                              hipStream_t stream) {
  const float* x      = (const float*)d_in[0];
  const float* W      = (const float*)d_in[1];
  const int*   labels = (const int*)d_in[2];
  float* out = (float*)d_out;

  // ws layout: xb [640*1024 bf16] | S [640 f32] | tgt [576 f32]  (~1.26 MB)
  char* ws = (char*)d_ws;
  unsigned short* xb = (unsigned short*)ws;
  float* S   = (float*)(ws + (size_t)MPAD * DIM * 2);
  float* tgt = (float*)(ws + (size_t)MPAD * DIM * 2 + MPAD * 4);

  hipMemsetAsync(S, 0, MPAD * sizeof(float), stream);   // zero accumulators
  k_cvt_x<<<MPAD * DIM / (256 * 8), 256, 0, stream>>>(x, xb);
  k_gemm<<<NWG, 512, 0, stream>>>(W, xb, S);
  k_tgt<<<N_TOK, 256, 0, stream>>>(x, W, labels, tgt);
  k_final<<<1, 256, 0, stream>>>(S, tgt, labels, out);
}

// Round 7
// 749.322 us; speedup vs baseline: 1.1731x; 1.1731x over previous
//
#include <hip/hip_runtime.h>
#include <hip/hip_bf16.h>

// Problem constants
#define N_TOK   576
#define MPAD    640            // padded to 5*128
#define DIM     1024
#define VOCAB   262400
#define BM      128
#define BN      128
#define BK      64
#define RB      5              // MPAD/BM row blocks
#define VBLKS   (VOCAB/BN)     // 2050
#define NWG     (RB*VBLKS)     // 10250
#define IGNORE_INDEX (-100)

typedef float f32x4 __attribute__((ext_vector_type(4)));

__device__ __forceinline__ int cvt4_fp8(float4 v) {
  int r = __builtin_amdgcn_cvt_pk_fp8_f32(v.x, v.y, 0, false);   // bytes 0,1
  r     = __builtin_amdgcn_cvt_pk_fp8_f32(v.z, v.w, r, true);    // bytes 2,3
  return r;
}

// ---------- kernel 1: x fp32 -> fp8 e4m3, rows [576,640) zero-padded ----------
__global__ void k_cvt_x(const float* __restrict__ x, unsigned char* __restrict__ xq) {
  int idx = blockIdx.x * 256 + threadIdx.x;     // 81920 threads * 8 elems
  long e0 = (long)idx * 8;
  int row = (int)(e0 >> 10);
  uint2 o;
  if (row < N_TOK) {
    float4 a = *(const float4*)(x + e0);
    float4 b = *(const float4*)(x + e0 + 4);
    o.x = (unsigned)cvt4_fp8(a);
    o.y = (unsigned)cvt4_fp8(b);
  } else {
    o.x = o.y = 0u;
  }
  *(uint2*)(xq + e0) = o;
}

// ---------- kernel 2: fp8 GEMM + softcap + exp + row-sum ----------
// R2's proven 2-barrier single-buffer structure, operands in fp8 e4m3:
// LDS = A 8KB + B 8KB (halved frag-read traffic, 5+ waves/SIMD occupancy).
// LDS layout (both tiles): 8B chunk c of row r stored at chunk (c ^ (r&7))
// within the 64B row -> frag ds_read_b64 spread 2/bank (free).
// A reg-staged from pre-converted Xq (16B loads -> 2x 8B swizzled ds_write).
// B reg-staged from W fp32, packed via v_cvt_pk_fp8_f32.
// MFMA: f32_16x16x32_fp8_fp8 (i64 operands, 8 k-bytes/lane). A/B use the
// identical slot->k loading so any HW slot permutation cancels in the dot.
// Target logit stays exact fp32 (k_tgt) -> loss error ~ lse noise only.
__global__ __launch_bounds__(256, 2) void k_gemm(
    const float* __restrict__ W,            // [VOCAB][DIM] fp32
    const unsigned char* __restrict__ Xq,   // [MPAD][DIM] fp8
    float* __restrict__ S)                  // [MPAD] running sum of exp(z-30)
{
  __shared__ unsigned char Asl[BM * BK];    // 8 KB, swizzled fp8
  __shared__ unsigned char Bsl[BN * BK];    // 8 KB, swizzled fp8

  // ---- bijective XCD swizzle (m204), rb-fastest logical order ----
  const int q  = NWG / 8, rm = NWG % 8;     // 1281, 2
  const int orig = blockIdx.x;
  const int xcd  = orig & 7;
  const int part = orig >> 3;
  const int bid  = (xcd < rm ? xcd * (q + 1) : rm * (q + 1) + (xcd - rm) * q) + part;

  const int rb  = bid % RB;
  const int vb  = bid / RB;
  const int m0  = rb * BM;
  const long n0 = (long)vb * BN;

  const int t   = threadIdx.x;
  const int l   = t & 63;
  const int w   = t >> 6;
  const int wm  = w >> 1, wn = w & 1;       // 2x2 wave grid, 64x64 per wave
  const int l15 = l & 15, lh = l >> 4;
  const int e8  = l15 & 7;

  // ---- staging geometry (constant per thread) ----
  // A: 2 x 16B global chunks -> 4 x 8B swizzled LDS writes
  int aoff[2][2];
  const unsigned char* asrc[2];
  #pragma unroll
  for (int i = 0; i < 2; ++i) {
    int lin  = t + i * 256;                 // 0..511
    int arow = lin >> 2;                    // 0..127
    int ac16 = lin & 3;                     // 16B chunk in row
    asrc[i] = Xq + (size_t)(m0 + arow) * DIM + ac16 * 16;
    aoff[i][0] = arow * BK + (((2 * ac16)     ^ (arow & 7)) * 8);
    aoff[i][1] = arow * BK + (((2 * ac16 + 1) ^ (arow & 7)) * 8);
  }
  // B: row t>>1, k-half (t&1)*32 ; 8 float4 loads -> 4 x 8B swizzled writes
  const int brow = t >> 1, bh = t & 1;
  const float* bsrc = W + (n0 + brow) * DIM + bh * 32;
  int boff[4];
  #pragma unroll
  for (int c = 0; c < 4; ++c)
    boff[c] = brow * BK + (((bh * 4 + c) ^ (brow & 7)) * 8);

  // frag read offsets (within-row swizzled chunk), row pitch 64B
  const int ck0 = ((0 * 4 + lh) ^ e8) * 8;  // kk=0
  const int ck1 = ((1 * 4 + lh) ^ e8) * 8;  // kk=1

  f32x4 acc[4][4];
  const f32x4 zero4 = {0.0f, 0.0f, 0.0f, 0.0f};
  #pragma unroll
  for (int i = 0; i < 4; ++i)
    #pragma unroll
    for (int j = 0; j < 4; ++j) acc[i][j] = zero4;

  for (int k0 = 0; k0 < DIM; k0 += BK) {
    // ---- issue ALL global loads before the barrier (latency overlap) ----
    float4 f[8];
    #pragma unroll
    for (int i = 0; i < 8; ++i) f[i] = *(const float4*)(bsrc + k0 + i * 4);
    uint4 ua[2];
    #pragma unroll
    for (int i = 0; i < 2; ++i) ua[i] = *(const uint4*)(asrc[i] + k0);

    __syncthreads();                        // prev-iter LDS reads done

    // ---- A: 4 x 8B swizzled writes ----
    #pragma unroll
    for (int i = 0; i < 2; ++i) {
      *(uint2*)(Asl + aoff[i][0]) = make_uint2(ua[i].x, ua[i].y);
      *(uint2*)(Asl + aoff[i][1]) = make_uint2(ua[i].z, ua[i].w);
    }
    // ---- B: fp32 -> fp8 pack + 4 x 8B swizzled writes ----
    #pragma unroll
    for (int c = 0; c < 4; ++c) {
      int lo = cvt4_fp8(f[2 * c]);
      int hi = cvt4_fp8(f[2 * c + 1]);
      *(int2*)(Bsl + boff[c]) = make_int2(lo, hi);
    }
    __syncthreads();

    // ---- fragments (ds_read_b64, swizzled) + MFMA ----
    long af[4][2], bf[4][2];
    #pragma unroll
    for (int mi = 0; mi < 4; ++mi) {
      const unsigned char* base = Asl + (wm * 64 + mi * 16 + l15) * BK;
      af[mi][0] = *(const long*)(base + ck0);
      af[mi][1] = *(const long*)(base + ck1);
    }
    #pragma unroll
    for (int ni = 0; ni < 4; ++ni) {
      const unsigned char* base = Bsl + (wn * 64 + ni * 16 + l15) * BK;
      bf[ni][0] = *(const long*)(base + ck0);
      bf[ni][1] = *(const long*)(base + ck1);
    }
    __builtin_amdgcn_s_setprio(1);
    #pragma unroll
    for (int kk = 0; kk < 2; ++kk)
      #pragma unroll
      for (int mi = 0; mi < 4; ++mi)
        #pragma unroll
        for (int ni = 0; ni < 4; ++ni)
          acc[mi][ni] = __builtin_amdgcn_mfma_f32_16x16x32_fp8_fp8(
              af[mi][kk], bf[ni][kk], acc[mi][ni], 0, 0, 0);
    __builtin_amdgcn_s_setprio(0);
  }

  // ---- epilogue: p = exp(z-30) = exp(-60/(exp(g/15)+1)), row sums, atomics
  // C frag layout (shape-determined): col = l&15 (vocab), row = lh*4 + j
  #pragma unroll
  for (int mi = 0; mi < 4; ++mi) {
    #pragma unroll
    for (int j = 0; j < 4; ++j) {
      float s = 0.0f;
      #pragma unroll
      for (int ni = 0; ni < 4; ++ni) {
        float g   = acc[mi][ni][j];
        float tp1 = __expf(g * (1.0f / 15.0f)) + 1.0f;
        s += __expf(-60.0f * __builtin_amdgcn_rcpf(tp1));
      }
      s += __shfl_xor(s, 1);
      s += __shfl_xor(s, 2);
      s += __shfl_xor(s, 4);
      s += __shfl_xor(s, 8);
      if (l15 == 0) {
        int row = m0 + wm * 64 + mi * 16 + lh * 4 + j;
        atomicAdd(&S[row], s);              // padded rows land in S[576..640)
      }
    }
  }
}

// ---------- kernel 3: exact fp32 target logits ----------
__global__ void k_tgt(const float* __restrict__ x, const float* __restrict__ W,
                      const int* __restrict__ labels, float* __restrict__ tgt) {
  int n = blockIdx.x;
  int lab = labels[n];
  int t = threadIdx.x;                       // 256 threads * 4 floats = 1024
  float s = 0.0f;
  if (lab >= 0) {
    const float4 a = ((const float4*)(x + (size_t)n * DIM))[t];
    const float4 b = ((const float4*)(W + (size_t)lab * DIM))[t];
    s = a.x*b.x + a.y*b.y + a.z*b.z + a.w*b.w;
  }
  #pragma unroll
  for (int off = 32; off >= 1; off >>= 1) s += __shfl_xor(s, off);
  __shared__ float wsum[4];
  if ((t & 63) == 0) wsum[t >> 6] = s;
  __syncthreads();
  if (t == 0) {
    float d = wsum[0] + wsum[1] + wsum[2] + wsum[3];
    tgt[n] = (lab >= 0) ? 30.0f * tanhf(d * (1.0f / 30.0f)) : 0.0f;
  }
}

// ---------- kernel 4: final reduce -> loss ----------
__global__ void k_final(const float* __restrict__ S, const float* __restrict__ tgt,
                        const int* __restrict__ labels, float* __restrict__ out) {
  int t = threadIdx.x;
  float sum = 0.0f, cnt = 0.0f;
  for (int n = t; n < N_TOK; n += 256) {
    if (labels[n] != IGNORE_INDEX) {
      sum += 30.0f + __logf(S[n]) - tgt[n];  // lse = 30 + log(sum exp(z-30))
      cnt += 1.0f;
    }
  }
  #pragma unroll
  for (int off = 32; off >= 1; off >>= 1) {
    sum += __shfl_xor(sum, off);
    cnt += __shfl_xor(cnt, off);
  }
  __shared__ float as_[4], ac_[4];
  if ((t & 63) == 0) { as_[t >> 6] = sum; ac_[t >> 6] = cnt; }
  __syncthreads();
  if (t == 0) {
    float ts = as_[0] + as_[1] + as_[2] + as_[3];
    float tc = ac_[0] + ac_[1] + ac_[2] + ac_[3];
    out[0] = ts / tc;
  }
}

extern "C" void kernel_launch(void* const* d_in, const int* in_sizes, int n_in,
                              void* d_out, int out_size, void* d_ws, size_t ws_size,
                              hipStream_t stream) {
  const float* x      = (const float*)d_in[0];
  const float* W      = (const float*)d_in[1];
  const int*   labels = (const int*)d_in[2];
  float* out = (float*)d_out;

  // ws layout: xq [640*1024 fp8] | S [640 f32] | tgt [576 f32]  (~0.66 MB)
  char* ws = (char*)d_ws;
  unsigned char* xq = (unsigned char*)ws;
  float* S   = (float*)(ws + (size_t)MPAD * DIM);
  float* tgt = (float*)(ws + (size_t)MPAD * DIM + MPAD * 4);

  hipMemsetAsync(S, 0, MPAD * sizeof(float), stream);   // zero accumulators
  k_cvt_x<<<MPAD * DIM / (256 * 8), 256, 0, stream>>>(x, xq);
  k_gemm<<<NWG, 256, 0, stream>>>(W, xq, S);
  k_tgt<<<N_TOK, 256, 0, stream>>>(x, W, labels, tgt);
  k_final<<<1, 256, 0, stream>>>(S, tgt, labels, out);
}

// Round 8
// 733.065 us; speedup vs baseline: 1.1991x; 1.0222x over previous
//
#include <hip/hip_runtime.h>
#include <hip/hip_bf16.h>

// Problem constants
#define N_TOK   576
#define MPAD    640            // padded to 5*128
#define DIM     1024
#define VOCAB   262400
#define BM      128
#define BN      128
#define RB      5              // MPAD/BM row blocks
#define VBLKS   (VOCAB/BN)     // 2050
#define NWG     (RB*VBLKS)     // 10250
#define IGNORE_INDEX (-100)

typedef float f32x4 __attribute__((ext_vector_type(4)));
typedef short  bf16x8 __attribute__((ext_vector_type(8)));
typedef unsigned short u16x8 __attribute__((ext_vector_type(8)));

#define AS1 __attribute__((address_space(1)))
#define AS3 __attribute__((address_space(3)))

__device__ __forceinline__ int cvt4_fp8(float4 v) {
  int r = __builtin_amdgcn_cvt_pk_fp8_f32(v.x, v.y, 0, false);   // bytes 0,1
  r     = __builtin_amdgcn_cvt_pk_fp8_f32(v.z, v.w, r, true);    // bytes 2,3
  return r;
}
__device__ __forceinline__ unsigned cvt_pk_bf16(float a, float b) {
  union { __hip_bfloat162 h; unsigned u; } c;
  c.h = __float22bfloat162_rn(make_float2(a, b));
  return c.u;
}

// ---------- W fp32 -> fp8 e4m3, streaming (HBM-bound ~215us) ----------
__global__ void k_cvt_w(const float* __restrict__ Wf, unsigned char* __restrict__ Wq) {
  const size_t TOT = (size_t)VOCAB * DIM;
  const size_t stride = (size_t)gridDim.x * blockDim.x * 16;
  for (size_t e0 = ((size_t)blockIdx.x * blockDim.x + threadIdx.x) * 16;
       e0 < TOT; e0 += stride) {
    float4 a = *(const float4*)(Wf + e0);
    float4 b = *(const float4*)(Wf + e0 + 4);
    float4 c = *(const float4*)(Wf + e0 + 8);
    float4 d = *(const float4*)(Wf + e0 + 12);
    uint4 o;
    o.x = (unsigned)cvt4_fp8(a);
    o.y = (unsigned)cvt4_fp8(b);
    o.z = (unsigned)cvt4_fp8(c);
    o.w = (unsigned)cvt4_fp8(d);
    *(uint4*)(Wq + e0) = o;
  }
}

// ---------- x fp32 -> fp8, rows [576,640) zero-padded ----------
__global__ void k_cvt_x_fp8(const float* __restrict__ x, unsigned char* __restrict__ xq) {
  int idx = blockIdx.x * 256 + threadIdx.x;
  long e0 = (long)idx * 8;
  int row = (int)(e0 >> 10);
  uint2 o;
  if (row < N_TOK) {
    float4 a = *(const float4*)(x + e0);
    float4 b = *(const float4*)(x + e0 + 4);
    o.x = (unsigned)cvt4_fp8(a);
    o.y = (unsigned)cvt4_fp8(b);
  } else { o.x = o.y = 0u; }
  *(uint2*)(xq + e0) = o;
}

// ---------- MAIN: fp8 GEMM, both operands global_load_lds, BK=128 ----------
// m145-class structure: no in-loop cvt, no reg staging. 128B fp8 rows =
// exactly R2's proven conflict-free geometry: 16B chunk j of row r stored
// at chunk (j ^ (r&7)); gload_lds dest linear, SOURCE pre-swizzled (m173).
// Frag ds_read_b64 at byte ((2kk+(lh>>1))^e8)*16 + (lh&1)*8: 2 lanes/bank
// pair = free. 8 K-steps, 2 barriers each (halved vs BK=64).
__global__ __launch_bounds__(256, 4) void k_gemm_fp8(
    const unsigned char* __restrict__ Wq,   // [VOCAB][DIM] fp8
    const unsigned char* __restrict__ Xq,   // [MPAD][DIM] fp8
    float* __restrict__ S)                  // [MPAD] running sum of exp(z-30)
{
  __shared__ unsigned char Asl[BM * 128];   // 16 KB
  __shared__ unsigned char Bsl[BN * 128];   // 16 KB

  // bijective XCD swizzle (m204), rb-fastest logical order
  const int q  = NWG / 8, rm = NWG % 8;     // 1281, 2
  const int orig = blockIdx.x;
  const int xcd  = orig & 7;
  const int part = orig >> 3;
  const int bid  = (xcd < rm ? xcd * (q + 1) : rm * (q + 1) + (xcd - rm) * q) + part;

  const int rb  = bid % RB;
  const int vb  = bid / RB;
  const int m0  = rb * BM;
  const long n0 = (long)vb * BN;

  const int t   = threadIdx.x;
  const int l   = t & 63;
  const int w   = t >> 6;
  const int wm  = w >> 1, wn = w & 1;       // 2x2 waves, 64x64 per wave
  const int l15 = l & 15, lh = l >> 4;
  const int e8  = l15 & 7;

  // staging: 4 x 16B chunks per thread per operand, source pre-swizzled
  const unsigned char* asrc[4];
  const unsigned char* bsrc[4];
  #pragma unroll
  for (int i = 0; i < 4; ++i) {
    int lin = t + i * 256;                  // 0..1023
    int r   = lin >> 3;                     // row 0..127
    int sj  = (lin & 7) ^ (r & 7);          // pre-swizzled source chunk
    asrc[i] = Xq + (size_t)(m0 + r) * DIM + sj * 16;
    bsrc[i] = Wq + (size_t)(n0 + r) * DIM + sj * 16;
  }
  // frag byte offsets per kk (swizzled read)
  int fo[4];
  #pragma unroll
  for (int kk = 0; kk < 4; ++kk)
    fo[kk] = (((2 * kk + (lh >> 1)) ^ e8) << 4) + ((lh & 1) << 3);

  f32x4 acc[4][4];
  const f32x4 zero4 = {0.0f, 0.0f, 0.0f, 0.0f};
  #pragma unroll
  for (int i = 0; i < 4; ++i)
    #pragma unroll
    for (int j = 0; j < 4; ++j) acc[i][j] = zero4;

  for (int k0 = 0; k0 < DIM; k0 += 128) {
    if (k0) __syncthreads();                // prev frag reads done
    #pragma unroll
    for (int i = 0; i < 4; ++i)
      __builtin_amdgcn_global_load_lds((const AS1 void*)(asrc[i] + k0),
          (AS3 void*)(Asl + (t + i * 256) * 16), 16, 0, 0);
    #pragma unroll
    for (int i = 0; i < 4; ++i)
      __builtin_amdgcn_global_load_lds((const AS1 void*)(bsrc[i] + k0),
          (AS3 void*)(Bsl + (t + i * 256) * 16), 16, 0, 0);
    __syncthreads();                        // drains vmcnt -> tiles ready

    __builtin_amdgcn_s_setprio(1);
    #pragma unroll
    for (int kk = 0; kk < 4; ++kk) {
      long af[4], bf[4];
      #pragma unroll
      for (int mi = 0; mi < 4; ++mi)
        af[mi] = *(const long*)(Asl + (wm * 64 + mi * 16 + l15) * 128 + fo[kk]);
      #pragma unroll
      for (int ni = 0; ni < 4; ++ni)
        bf[ni] = *(const long*)(Bsl + (wn * 64 + ni * 16 + l15) * 128 + fo[kk]);
      #pragma unroll
      for (int mi = 0; mi < 4; ++mi)
        #pragma unroll
        for (int ni = 0; ni < 4; ++ni)
          acc[mi][ni] = __builtin_amdgcn_mfma_f32_16x16x32_fp8_fp8(
              af[mi], bf[ni], acc[mi][ni], 0, 0, 0);
    }
    __builtin_amdgcn_s_setprio(0);
  }

  // epilogue: p = exp(z-30) = exp(-60/(exp(g/15)+1)); row sums; atomics
  #pragma unroll
  for (int mi = 0; mi < 4; ++mi) {
    #pragma unroll
    for (int j = 0; j < 4; ++j) {
      float s = 0.0f;
      #pragma unroll
      for (int ni = 0; ni < 4; ++ni) {
        float g   = acc[mi][ni][j];
        float tp1 = __expf(g * (1.0f / 15.0f)) + 1.0f;
        s += __expf(-60.0f * __builtin_amdgcn_rcpf(tp1));
      }
      s += __shfl_xor(s, 1);
      s += __shfl_xor(s, 2);
      s += __shfl_xor(s, 4);
      s += __shfl_xor(s, 8);
      if (l15 == 0) {
        int row = m0 + wm * 64 + mi * 16 + lh * 4 + j;
        atomicAdd(&S[row], s);
      }
    }
  }
}

// ================= FALLBACK (R2, bf16 reg-staged) if ws too small =========
__global__ void k_cvt_x_bf16(const float* __restrict__ x, unsigned short* __restrict__ xb) {
  int idx = blockIdx.x * 256 + threadIdx.x;
  long e0 = (long)idx * 8;
  int row = (int)(e0 >> 10);
  union { u16x8 v; unsigned u[4]; } o;
  if (row < N_TOK) {
    const float4 f0 = *(const float4*)(x + e0);
    const float4 f1 = *(const float4*)(x + e0 + 4);
    o.u[0] = cvt_pk_bf16(f0.x, f0.y);
    o.u[1] = cvt_pk_bf16(f0.z, f0.w);
    o.u[2] = cvt_pk_bf16(f1.x, f1.y);
    o.u[3] = cvt_pk_bf16(f1.z, f1.w);
  } else { o.u[0] = o.u[1] = o.u[2] = o.u[3] = 0u; }
  *(u16x8*)(xb + e0) = o.v;
}

__global__ __launch_bounds__(256, 2) void k_gemm_fb(
    const float* __restrict__ W, const unsigned short* __restrict__ Xb,
    float* __restrict__ S)
{
  __shared__ unsigned short As[BM * 64];
  __shared__ unsigned short Bs[BN * 64];
  const int q  = NWG / 8, rm = NWG % 8;
  const int orig = blockIdx.x;
  const int xcd  = orig & 7;
  const int part = orig >> 3;
  const int bid  = (xcd < rm ? xcd * (q + 1) : rm * (q + 1) + (xcd - rm) * q) + part;
  const int rb  = bid % RB;
  const int vb  = bid / RB;
  const int m0  = rb * BM;
  const long n0 = (long)vb * BN;
  const int t   = threadIdx.x;
  const int l   = t & 63;
  const int w   = t >> 6;
  const int wm  = w >> 1, wn = w & 1;
  const int l15 = l & 15, lh = l >> 4;
  const int e8  = l15 & 7;

  f32x4 acc[4][4];
  const f32x4 zero4 = {0.0f, 0.0f, 0.0f, 0.0f};
  #pragma unroll
  for (int i = 0; i < 4; ++i)
    #pragma unroll
    for (int j = 0; j < 4; ++j) acc[i][j] = zero4;

  for (int k0 = 0; k0 < DIM; k0 += 64) {
    float4 fb[4][2];
    #pragma unroll
    for (int i = 0; i < 4; ++i) {
      int lin = t + i * 256;
      int r   = lin >> 3;
      int ko  = (lin & 7) * 8;
      const float* g = W + (n0 + r) * DIM + k0 + ko;
      fb[i][0] = *(const float4*)g;
      fb[i][1] = *(const float4*)(g + 4);
    }
    __syncthreads();
    #pragma unroll
    for (int i = 0; i < 4; ++i) {
      int lin = t + i * 256;
      int r   = lin >> 3;
      int kb  = (lin & 7) ^ (r & 7);
      const unsigned short* g = Xb + (size_t)(m0 + r) * DIM + k0 + kb * 8;
      __builtin_amdgcn_global_load_lds((const AS1 void*)g,
          (AS3 void*)(As + (size_t)lin * 8), 16, 0, 0);
    }
    #pragma unroll
    for (int i = 0; i < 4; ++i) {
      int lin = t + i * 256;
      int r   = lin >> 3;
      int c   = (lin & 7) ^ (r & 7);
      union { u16x8 v; unsigned u[4]; } o;
      o.u[0] = cvt_pk_bf16(fb[i][0].x, fb[i][0].y);
      o.u[1] = cvt_pk_bf16(fb[i][0].z, fb[i][0].w);
      o.u[2] = cvt_pk_bf16(fb[i][1].x, fb[i][1].y);
      o.u[3] = cvt_pk_bf16(fb[i][1].z, fb[i][1].w);
      *(u16x8*)(Bs + r * 64 + c * 8) = o.v;
    }
    __syncthreads();
    bf16x8 af[4][2], bfr[4][2];
    #pragma unroll
    for (int mi = 0; mi < 4; ++mi)
      #pragma unroll
      for (int kk = 0; kk < 2; ++kk)
        af[mi][kk] = *(const bf16x8*)(As + (wm*64 + mi*16 + l15) * 64
                                         + (((kk*4 + lh) ^ e8) * 8));
    #pragma unroll
    for (int ni = 0; ni < 4; ++ni)
      #pragma unroll
      for (int kk = 0; kk < 2; ++kk)
        bfr[ni][kk] = *(const bf16x8*)(Bs + (wn*64 + ni*16 + l15) * 64
                                          + (((kk*4 + lh) ^ e8) * 8));
    #pragma unroll
    for (int kk = 0; kk < 2; ++kk)
      #pragma unroll
      for (int mi = 0; mi < 4; ++mi)
        #pragma unroll
        for (int ni = 0; ni < 4; ++ni)
          acc[mi][ni] = __builtin_amdgcn_mfma_f32_16x16x32_bf16(
              af[mi][kk], bfr[ni][kk], acc[mi][ni], 0, 0, 0);
  }
  #pragma unroll
  for (int mi = 0; mi < 4; ++mi) {
    #pragma unroll
    for (int j = 0; j < 4; ++j) {
      float s = 0.0f;
      #pragma unroll
      for (int ni = 0; ni < 4; ++ni) {
        float g   = acc[mi][ni][j];
        float tp1 = __expf(g * (1.0f / 15.0f)) + 1.0f;
        s += __expf(-60.0f * __builtin_amdgcn_rcpf(tp1));
      }
      s += __shfl_xor(s, 1);
      s += __shfl_xor(s, 2);
      s += __shfl_xor(s, 4);
      s += __shfl_xor(s, 8);
      if (l15 == 0) {
        int row = m0 + wm*64 + mi*16 + lh*4 + j;
        atomicAdd(&S[row], s);
      }
    }
  }
}

// ---------- exact fp32 target logits ----------
__global__ void k_tgt(const float* __restrict__ x, const float* __restrict__ W,
                      const int* __restrict__ labels, float* __restrict__ tgt) {
  int n = blockIdx.x;
  int lab = labels[n];
  int t = threadIdx.x;
  float s = 0.0f;
  if (lab >= 0) {
    const float4 a = ((const float4*)(x + (size_t)n * DIM))[t];
    const float4 b = ((const float4*)(W + (size_t)lab * DIM))[t];
    s = a.x*b.x + a.y*b.y + a.z*b.z + a.w*b.w;
  }
  #pragma unroll
  for (int off = 32; off >= 1; off >>= 1) s += __shfl_xor(s, off);
  __shared__ float wsum[4];
  if ((t & 63) == 0) wsum[t >> 6] = s;
  __syncthreads();
  if (t == 0) {
    float d = wsum[0] + wsum[1] + wsum[2] + wsum[3];
    tgt[n] = (lab >= 0) ? 30.0f * tanhf(d * (1.0f / 30.0f)) : 0.0f;
  }
}

// ---------- final reduce -> loss ----------
__global__ void k_final(const float* __restrict__ S, const float* __restrict__ tgt,
                        const int* __restrict__ labels, float* __restrict__ out) {
  int t = threadIdx.x;
  float sum = 0.0f, cnt = 0.0f;
  for (int n = t; n < N_TOK; n += 256) {
    if (labels[n] != IGNORE_INDEX) {
      sum += 30.0f + __logf(S[n]) - tgt[n];
      cnt += 1.0f;
    }
  }
  #pragma unroll
  for (int off = 32; off >= 1; off >>= 1) {
    sum += __shfl_xor(sum, off);
    cnt += __shfl_xor(cnt, off);
  }
  __shared__ float as_[4], ac_[4];
  if ((t & 63) == 0) { as_[t >> 6] = sum; ac_[t >> 6] = cnt; }
  __syncthreads();
  if (t == 0) out[0] = (as_[0]+as_[1]+as_[2]+as_[3]) / (ac_[0]+ac_[1]+ac_[2]+ac_[3]);
}

extern "C" void kernel_launch(void* const* d_in, const int* in_sizes, int n_in,
                              void* d_out, int out_size, void* d_ws, size_t ws_size,
                              hipStream_t stream) {
  const float* x      = (const float*)d_in[0];
  const float* W      = (const float*)d_in[1];
  const int*   labels = (const int*)d_in[2];
  float* out = (float*)d_out;
  char* ws = (char*)d_ws;

  const size_t WQ_BYTES = (size_t)VOCAB * DIM;          // 268.7 MB
  const size_t XQ_BYTES = (size_t)MPAD * DIM;           // 0.64 MB
  const size_t NEED = WQ_BYTES + XQ_BYTES + (MPAD + N_TOK) * sizeof(float);

  if (ws_size >= NEED) {
    // fp8 path: Wq | xq | S | tgt
    unsigned char* Wq = (unsigned char*)ws;
    unsigned char* xq = (unsigned char*)(ws + WQ_BYTES);
    float* S   = (float*)(ws + WQ_BYTES + XQ_BYTES);
    float* tgt = S + MPAD;
    hipMemsetAsync(S, 0, MPAD * sizeof(float), stream);
    k_cvt_w<<<2048, 256, 0, stream>>>(W, Wq);
    k_cvt_x_fp8<<<MPAD * DIM / (256 * 8), 256, 0, stream>>>(x, xq);
    k_gemm_fp8<<<NWG, 256, 0, stream>>>(Wq, xq, S);
    k_tgt<<<N_TOK, 256, 0, stream>>>(x, W, labels, tgt);
    k_final<<<1, 256, 0, stream>>>(S, tgt, labels, out);
  } else {
    // fallback: R2 structure. ws: xb bf16 | S | tgt
    unsigned short* xb = (unsigned short*)ws;
    float* S   = (float*)(ws + (size_t)MPAD * DIM * 2);
    float* tgt = S + MPAD;
    hipMemsetAsync(S, 0, MPAD * sizeof(float), stream);
    k_cvt_x_bf16<<<MPAD * DIM / (256 * 8), 256, 0, stream>>>(x, xb);
    k_gemm_fb<<<NWG, 256, 0, stream>>>(W, xb, S);
    k_tgt<<<N_TOK, 256, 0, stream>>>(x, W, labels, tgt);
    k_final<<<1, 256, 0, stream>>>(S, tgt, labels, out);
  }
}

// Round 9
// 484.426 us; speedup vs baseline: 1.8145x; 1.5133x over previous
//
#include <hip/hip_runtime.h>
#include <hip/hip_bf16.h>

// Problem constants
#define N_TOK   576
#define MPAD    640            // padded to 5*128
#define DIM     1024
#define VOCAB   262400
#define BM      128
#define BN      128
#define BK      64             // k-elements per step (fp8: 64 B rows)
#define RB      5              // MPAD/BM row blocks
#define VBLKS   (VOCAB/BN)     // 2050
#define NWG     (RB*VBLKS)     // 10250
#define IGNORE_INDEX (-100)

typedef float f32x4 __attribute__((ext_vector_type(4)));

#define AS1 __attribute__((address_space(1)))
#define AS3 __attribute__((address_space(3)))

__device__ __forceinline__ int cvt4_fp8(float4 v) {
  int r = __builtin_amdgcn_cvt_pk_fp8_f32(v.x, v.y, 0, false);   // bytes 0,1
  r     = __builtin_amdgcn_cvt_pk_fp8_f32(v.z, v.w, r, true);    // bytes 2,3
  return r;
}

// ---------- kernel 1: x fp32 -> fp8 e4m3, rows [576,640) zero-padded ----------
__global__ void k_cvt_x(const float* __restrict__ x, unsigned char* __restrict__ xq) {
  int idx = blockIdx.x * 256 + threadIdx.x;
  long e0 = (long)idx * 8;
  int row = (int)(e0 >> 10);
  uint2 o;
  if (row < N_TOK) {
    float4 a = *(const float4*)(x + e0);
    float4 b = *(const float4*)(x + e0 + 4);
    o.x = (unsigned)cvt4_fp8(a);
    o.y = (unsigned)cvt4_fp8(b);
  } else { o.x = o.y = 0u; }
  *(uint2*)(xq + e0) = o;
}

// ---------- kernel 2: single-pass fp8 GEMM + softcap + exp + row-sum ----------
// R2's proven 2-barrier skeleton; LDS tiles fp8 with PAIRED-ROW layout:
// two 64B rows share a 128B LDS line. Row r -> pair p=r>>1, parity s=r&1;
// 16B chunk j of row r stored at combined slot ((s*4+j) ^ (p&7)) within the
// line. Every 16-lane phase group covers all 8 bank-quads (2x aliasing =
// free, m136). Halves ALL LDS traffic vs R2; MFMA count unchanged
// (fp8 16x16x32 = bf16 rate); B global loads + cvt VALU identical to R2.
// A staged via global_load_lds (linear dest, inverse-swizzled source);
// B reg-staged fp32 -> v_cvt_pk_fp8 -> swizzled ds_write_b64.
__global__ __launch_bounds__(256, 4) void k_gemm(
    const float* __restrict__ W,            // [VOCAB][DIM] fp32
    const unsigned char* __restrict__ Xq,   // [MPAD][DIM] fp8
    float* __restrict__ S)                  // [MPAD] running sum of exp(z-30)
{
  __shared__ unsigned char Asl[BM * BK];    // 8 KB (64 pair-lines x 128 B)
  __shared__ unsigned char Bsl[BN * BK];    // 8 KB

  // ---- bijective XCD swizzle (m204), rb-fastest logical order ----
  const int q  = NWG / 8, rm = NWG % 8;     // 1281, 2
  const int orig = blockIdx.x;
  const int xcd  = orig & 7;
  const int part = orig >> 3;
  const int bid  = (xcd < rm ? xcd * (q + 1) : rm * (q + 1) + (xcd - rm) * q) + part;

  const int rb  = bid % RB;
  const int vb  = bid / RB;
  const int m0  = rb * BM;
  const long n0 = (long)vb * BN;

  const int t   = threadIdx.x;
  const int l   = t & 63;
  const int w   = t >> 6;
  const int wm  = w >> 1, wn = w & 1;       // 2x2 waves, 64x64 per wave
  const int l15 = l & 15, lh = l >> 4;

  // ---- A staging: global_load_lds, linear dest, inverse-swizzled source ----
  // dest chunk lin -> (p = lin>>3, slot = lin&7); source chunk c = slot^(p&7)
  // -> source row 2p+(c>>2), byte (c&3)*16.
  const unsigned char* asrc[2];
  #pragma unroll
  for (int i = 0; i < 2; ++i) {
    int lin = t + i * 256;                  // 0..511
    int p   = lin >> 3;
    int c   = (lin & 7) ^ (p & 7);
    asrc[i] = Xq + (size_t)(m0 + 2 * p + (c >> 2)) * DIM + (c & 3) * 16;
  }
  // ---- B staging: 8 floats/thread/i -> 8 fp8 at swizzled 8B slot ----
  const float* bsrc[4];
  int boff[4];
  #pragma unroll
  for (int i = 0; i < 4; ++i) {
    int lin = t + i * 256;                  // 0..1023
    int r   = lin >> 3;                     // row 0..127
    int ko  = (lin & 7) * 8;                // element offset in row
    bsrc[i] = W + (n0 + r) * DIM + ko;
    int p = r >> 1, s = r & 1;
    int jj = (lin & 7) >> 1, hb = lin & 1;  // 16B chunk, 8B half
    boff[i] = p * 128 + ((((s << 2) | jj) ^ (p & 7)) << 4) + (hb << 3);
  }
  // ---- frag read offsets (paired-row swizzle) ----
  // row = base16*16 + l15 -> p = base16*8 + (l15>>1) (base16 multiple of 16
  // rows -> p&7 = l15>>1); slot = ((l15&1)*4 | (kk*2+(lh>>1))) ^ (l15>>1)
  const int pr = l15 >> 1, sr = l15 & 1;
  int fo[2];
  #pragma unroll
  for (int kk = 0; kk < 2; ++kk)
    fo[kk] = pr * 128 + (((((sr << 2) | (kk * 2 + (lh >> 1))) ^ pr)) << 4)
           + ((lh & 1) << 3);
  const int abase = wm * 4096;              // wm*64 rows = wm*32 pairs
  const int bbase = wn * 4096;

  f32x4 acc[4][4];
  const f32x4 zero4 = {0.0f, 0.0f, 0.0f, 0.0f};
  #pragma unroll
  for (int i = 0; i < 4; ++i)
    #pragma unroll
    for (int j = 0; j < 4; ++j) acc[i][j] = zero4;

  for (int k0 = 0; k0 < DIM; k0 += BK) {
    // -- B global loads issued BEFORE the barrier (hide under prev MFMA) --
    float4 fb[4][2];
    #pragma unroll
    for (int i = 0; i < 4; ++i) {
      fb[i][0] = *(const float4*)(bsrc[i] + k0);
      fb[i][1] = *(const float4*)(bsrc[i] + k0 + 4);
    }
    __syncthreads();                        // prev-iter frag reads done
    // -- A: 2 x 16B direct global->LDS --
    #pragma unroll
    for (int i = 0; i < 2; ++i)
      __builtin_amdgcn_global_load_lds((const AS1 void*)(asrc[i] + k0),
          (AS3 void*)(Asl + (t + i * 256) * 16), 16, 0, 0);
    // -- B: cvt fp32->fp8, swizzled 8B writes --
    #pragma unroll
    for (int i = 0; i < 4; ++i) {
      int lo = cvt4_fp8(fb[i][0]);
      int hi = cvt4_fp8(fb[i][1]);
      *(int2*)(Bsl + boff[i]) = make_int2(lo, hi);
    }
    __syncthreads();                        // drains vmcnt+lgkmcnt: tiles ready

    // -- fragments (ds_read_b64, conflict-free) + MFMA --
    long af[4][2], bf[4][2];
    #pragma unroll
    for (int mi = 0; mi < 4; ++mi) {
      af[mi][0] = *(const long*)(Asl + abase + mi * 1024 + fo[0]);
      af[mi][1] = *(const long*)(Asl + abase + mi * 1024 + fo[1]);
    }
    #pragma unroll
    for (int ni = 0; ni < 4; ++ni) {
      bf[ni][0] = *(const long*)(Bsl + bbase + ni * 1024 + fo[0]);
      bf[ni][1] = *(const long*)(Bsl + bbase + ni * 1024 + fo[1]);
    }
    __builtin_amdgcn_s_setprio(1);
    #pragma unroll
    for (int kk = 0; kk < 2; ++kk)
      #pragma unroll
      for (int mi = 0; mi < 4; ++mi)
        #pragma unroll
        for (int ni = 0; ni < 4; ++ni)
          acc[mi][ni] = __builtin_amdgcn_mfma_f32_16x16x32_fp8_fp8(
              af[mi][kk], bf[ni][kk], acc[mi][ni], 0, 0, 0);
    __builtin_amdgcn_s_setprio(0);
  }

  // ---- epilogue: p = exp(z-30) = exp(-60/(exp(g/15)+1)); row sums; atomics
  // C frag layout (shape-determined, HW-validated R7/R8): col=l15, row=lh*4+j
  #pragma unroll
  for (int mi = 0; mi < 4; ++mi) {
    #pragma unroll
    for (int j = 0; j < 4; ++j) {
      float s = 0.0f;
      #pragma unroll
      for (int ni = 0; ni < 4; ++ni) {
        float g   = acc[mi][ni][j];
        float tp1 = __expf(g * (1.0f / 15.0f)) + 1.0f;
        s += __expf(-60.0f * __builtin_amdgcn_rcpf(tp1));
      }
      s += __shfl_xor(s, 1);
      s += __shfl_xor(s, 2);
      s += __shfl_xor(s, 4);
      s += __shfl_xor(s, 8);
      if (l15 == 0) {
        int row = m0 + wm * 64 + mi * 16 + lh * 4 + j;
        atomicAdd(&S[row], s);              // padded rows land in S[576..640)
      }
    }
  }
}

// ---------- kernel 3: exact fp32 target logits ----------
__global__ void k_tgt(const float* __restrict__ x, const float* __restrict__ W,
                      const int* __restrict__ labels, float* __restrict__ tgt) {
  int n = blockIdx.x;
  int lab = labels[n];
  int t = threadIdx.x;
  float s = 0.0f;
  if (lab >= 0) {
    const float4 a = ((const float4*)(x + (size_t)n * DIM))[t];
    const float4 b = ((const float4*)(W + (size_t)lab * DIM))[t];
    s = a.x*b.x + a.y*b.y + a.z*b.z + a.w*b.w;
  }
  #pragma unroll
  for (int off = 32; off >= 1; off >>= 1) s += __shfl_xor(s, off);
  __shared__ float wsum[4];
  if ((t & 63) == 0) wsum[t >> 6] = s;
  __syncthreads();
  if (t == 0) {
    float d = wsum[0] + wsum[1] + wsum[2] + wsum[3];
    tgt[n] = (lab >= 0) ? 30.0f * tanhf(d * (1.0f / 30.0f)) : 0.0f;
  }
}

// ---------- kernel 4: final reduce -> loss ----------
__global__ void k_final(const float* __restrict__ S, const float* __restrict__ tgt,
                        const int* __restrict__ labels, float* __restrict__ out) {
  int t = threadIdx.x;
  float sum = 0.0f, cnt = 0.0f;
  for (int n = t; n < N_TOK; n += 256) {
    if (labels[n] != IGNORE_INDEX) {
      sum += 30.0f + __logf(S[n]) - tgt[n];  // lse = 30 + log(sum exp(z-30))
      cnt += 1.0f;
    }
  }
  #pragma unroll
  for (int off = 32; off >= 1; off >>= 1) {
    sum += __shfl_xor(sum, off);
    cnt += __shfl_xor(cnt, off);
  }
  __shared__ float as_[4], ac_[4];
  if ((t & 63) == 0) { as_[t >> 6] = sum; ac_[t >> 6] = cnt; }
  __syncthreads();
  if (t == 0) out[0] = (as_[0]+as_[1]+as_[2]+as_[3]) / (ac_[0]+ac_[1]+ac_[2]+ac_[3]);
}

extern "C" void kernel_launch(void* const* d_in, const int* in_sizes, int n_in,
                              void* d_out, int out_size, void* d_ws, size_t ws_size,
                              hipStream_t stream) {
  const float* x      = (const float*)d_in[0];
  const float* W      = (const float*)d_in[1];
  const int*   labels = (const int*)d_in[2];
  float* out = (float*)d_out;

  // ws layout: xq [640*1024 fp8] | S [640 f32] | tgt [576 f32]  (~0.66 MB)
  char* ws = (char*)d_ws;
  unsigned char* xq = (unsigned char*)ws;
  float* S   = (float*)(ws + (size_t)MPAD * DIM);
  float* tgt = S + MPAD;

  hipMemsetAsync(S, 0, MPAD * sizeof(float), stream);   // zero accumulators
  k_cvt_x<<<MPAD * DIM / (256 * 8), 256, 0, stream>>>(x, xq);
  k_gemm<<<NWG, 256, 0, stream>>>(W, xq, S);
  k_tgt<<<N_TOK, 256, 0, stream>>>(x, W, labels, tgt);
  k_final<<<1, 256, 0, stream>>>(S, tgt, labels, out);
}